// Round 1
// baseline (332.184 us; speedup 1.0000x reference)
//
#include <hip/hip_runtime.h>
#include <hip/hip_bf16.h>
#include <cstdint>
#include <cstddef>

#define KSZ 5
#define KK 25
#define EMB 64
#define CC 128
#define FILTERS 128

typedef __attribute__((ext_vector_type(8))) short short8;
typedef __attribute__((ext_vector_type(4))) float floatx4;

__device__ inline unsigned short f32_to_bf16(float f) {
    union { float f; unsigned u; } v; v.f = f;
    unsigned u = v.u;
    unsigned r = u + 0x7FFF + ((u >> 16) & 1);
    return (unsigned short)(r >> 16);
}

// ---------------- gate: sigmoid(coarse @ w_gate + b) at coarse res ----------------
__global__ void gate_kernel(const float* __restrict__ coarse,
                            const float* __restrict__ w_gate,
                            const float* __restrict__ b_gate,
                            float* __restrict__ gate, int npix) {
    int wave = (blockIdx.x * blockDim.x + threadIdx.x) >> 6;
    int lane = threadIdx.x & 63;
    if (wave >= npix) return;
    const float* src = coarse + (size_t)wave * CC;
    float acc = src[lane] * w_gate[lane] + src[lane + 64] * w_gate[lane + 64];
    #pragma unroll
    for (int off = 32; off > 0; off >>= 1)
        acc += __shfl_down(acc, off, 64);
    if (lane == 0) {
        float z = acc + b_gate[0];
        gate[wave] = 1.0f / (1.0f + __expf(-z));
    }
}

// ---------------- 1x1 embed: y[M,64] = x[M,Cin] @ w[Cin,64] (+bias) ----------------
__global__ void embed_kernel(const float* __restrict__ x,
                             const float* __restrict__ w,
                             const float* __restrict__ bias,
                             float* __restrict__ y, int M, int Cin) {
    int n = threadIdx.x;                         // 0..63
    int row = blockIdx.x * blockDim.y + threadIdx.y;
    if (row >= M) return;
    const float* xr = x + (size_t)row * Cin;
    float acc = bias ? bias[n] : 0.0f;
    for (int k = 0; k < Cin; ++k)
        acc += xr[k] * w[k * EMB + n];
    y[(size_t)row * EMB + n] = acc;
}

// ---------------- 3x3 content conv: [B,Hh,Ww,64] -> [B,Hh,Ww,25], SAME pad ----------------
__global__ void content_conv_kernel(const float* __restrict__ x,
                                    const float* __restrict__ w,   // [3,3,64,25]
                                    const float* __restrict__ bias,// [25]
                                    float* __restrict__ y,
                                    int Hh, int Ww) {
    int q = blockIdx.x * blockDim.x + threadIdx.x;
    int npix_img = Hh * Ww;
    int b = q / npix_img;
    int rem = q - b * npix_img;
    int y0 = rem / Ww;
    int x0 = rem - y0 * Ww;
    float acc[KK];
    #pragma unroll
    for (int k = 0; k < KK; ++k) acc[k] = bias[k];
    for (int dy = 0; dy < 3; ++dy) {
        int yy = y0 + dy - 1;
        if (yy < 0 || yy >= Hh) continue;
        for (int dx = 0; dx < 3; ++dx) {
            int xx = x0 + dx - 1;
            if (xx < 0 || xx >= Ww) continue;
            const float* xp = x + (((size_t)(b * Hh + yy)) * Ww + xx) * EMB;
            const float* wp = w + ((dy * 3 + dx) * EMB) * KK;
            for (int e = 0; e < EMB; ++e) {
                float v = xp[e];
                #pragma unroll
                for (int k = 0; k < KK; ++k)
                    acc[k] += v * wp[e * KK + k];
            }
        }
    }
    float* yp = y + (size_t)q * KK;
    #pragma unroll
    for (int k = 0; k < KK; ++k) yp[k] = acc[k];
}

// ---------------- fused softmax + CARAFE (faithful reshape), out bf16 ----------------
// one block per coarse pixel; 4 waves = the 4 upsampled fine pixels
__global__ void carafe_kernel(const float* __restrict__ coarse,  // [B,h,w,128]
                              const float* __restrict__ f_conv,  // [B,H,W,25]
                              const float* __restrict__ c_conv,  // [B,h,w,25]
                              unsigned short* __restrict__ xout, // bf16 [B,H,W,128]
                              int h, int w) {
    __shared__ float patch[KK * CC];   // [pos 25][ch 128] flat = faithful layout
    int cpix = blockIdx.x;
    int npix_img = h * w;
    int b = cpix / npix_img;
    int rem = cpix - b * npix_img;
    int cy = rem / w;
    int cx = rem - cy * w;
    for (int i = threadIdx.x; i < KK * CC; i += blockDim.x) {
        int p = i >> 7, ch = i & 127;
        int py = cy + (p / KSZ) - 2, px = cx + (p % KSZ) - 2;
        float v = 0.0f;
        if (py >= 0 && py < h && px >= 0 && px < w)
            v = coarse[(((size_t)(b * h + py)) * w + px) * CC + ch];
        patch[i] = v;
    }
    __syncthreads();
    int wid = threadIdx.x >> 6;
    int lane = threadIdx.x & 63;
    int H = 2 * h, W = 2 * w;
    int fy = 2 * cy + (wid >> 1);
    int fx = 2 * cx + (wid & 1);
    size_t fq = ((size_t)(b * H + fy)) * W + fx;
    const float* fc = f_conv + fq * KK;
    const float* cc2 = c_conv + (size_t)cpix * KK;
    float lg[KK];
    float m = -1e30f;
    #pragma unroll
    for (int k = 0; k < KK; ++k) {
        lg[k] = fc[k] + cc2[k];
        m = fmaxf(m, lg[k]);
    }
    float s = 0.0f;
    #pragma unroll
    for (int k = 0; k < KK; ++k) {
        lg[k] = __expf(lg[k] - m);
        s += lg[k];
    }
    float inv = 1.0f / s;
    unsigned short* outp = xout + fq * CC;
    #pragma unroll
    for (int cp = 0; cp < 2; ++cp) {
        int c = lane + 64 * cp;
        const float* pp = patch + c * KK;   // flat indices c*25+k  (faithful reshape)
        float acc = 0.0f;
        #pragma unroll
        for (int k = 0; k < KK; ++k)
            acc += lg[k] * pp[k];
        outp[c] = f32_to_bf16(acc * inv);
    }
}

// ---------------- weight transpose + bf16 convert: wT[o*128+k] = w[k*128+o] ----------------
__global__ void wtrans_kernel(const float* __restrict__ w,
                              unsigned short* __restrict__ wT, int n) {
    int i = blockIdx.x * blockDim.x + threadIdx.x;
    if (i >= n) return;
    int o = i >> 7, k = i & 127;
    wT[i] = f32_to_bf16(w[k * 128 + o]);
}

// ---------------- fused final: out = g*(co@Wf+bf) + (1-g)*co, co = X@Wc+bc ----------------
#define LDSP 136   // padded LDS row stride (bf16 elems): 272B -> conflict-free b128 reads
__global__ __launch_bounds__(256) void final_kernel(
        const unsigned short* __restrict__ X,    // bf16 [M,128]
        const unsigned short* __restrict__ WcT,  // bf16 [o][k]
        const unsigned short* __restrict__ WfT,  // bf16 [p][o]
        const float* __restrict__ b_coarse,
        const float* __restrict__ b_fineout,
        const float* __restrict__ gate,          // [B*h*w]
        float* __restrict__ out) {
    __shared__ unsigned short Xs[128 * LDSP];
    __shared__ unsigned short Ws[128 * LDSP];
    int tid = threadIdx.x;
    int row0 = blockIdx.x * 128;

    {
        const uint4* src = (const uint4*)(X + (size_t)row0 * 128);
        const uint4* wsrc = (const uint4*)WcT;
        for (int ci = tid; ci < 2048; ci += 256) {
            int r = ci >> 4, c = ci & 15;
            *(uint4*)(&Xs[r * LDSP + c * 8]) = src[ci];
            *(uint4*)(&Ws[r * LDSP + c * 8]) = wsrc[ci];
        }
    }
    __syncthreads();

    int wid = tid >> 6, lane = tid & 63;
    int wm = wid >> 1, wn = wid & 1;
    int lr = lane & 15;
    int lk = (lane >> 4) * 8;
    int lrow4 = (lane >> 4) * 4;

    floatx4 acc1[4][4];
    #pragma unroll
    for (int mi = 0; mi < 4; ++mi)
        #pragma unroll
        for (int ni = 0; ni < 4; ++ni)
            acc1[mi][ni] = (floatx4){0.f, 0.f, 0.f, 0.f};

    #pragma unroll
    for (int kk = 0; kk < 128; kk += 32) {
        short8 a[4], bb[4];
        #pragma unroll
        for (int mi = 0; mi < 4; ++mi)
            a[mi] = *(const short8*)(&Xs[(wm * 64 + mi * 16 + lr) * LDSP + kk + lk]);
        #pragma unroll
        for (int ni = 0; ni < 4; ++ni)
            bb[ni] = *(const short8*)(&Ws[(wn * 64 + ni * 16 + lr) * LDSP + kk + lk]);
        #pragma unroll
        for (int mi = 0; mi < 4; ++mi)
            #pragma unroll
            for (int ni = 0; ni < 4; ++ni)
                acc1[mi][ni] = __builtin_amdgcn_mfma_f32_16x16x32_bf16(a[mi], bb[ni], acc1[mi][ni], 0, 0, 0);
    }
    __syncthreads();   // done reading Xs/Ws

    // stage Wf; write CO (with bias) back into Xs as bf16
    {
        const uint4* wsrc = (const uint4*)WfT;
        for (int ci = tid; ci < 2048; ci += 256) {
            int r = ci >> 4, c = ci & 15;
            *(uint4*)(&Ws[r * LDSP + c * 8]) = wsrc[ci];
        }
    }
    #pragma unroll
    for (int mi = 0; mi < 4; ++mi) {
        #pragma unroll
        for (int ni = 0; ni < 4; ++ni) {
            int col = wn * 64 + ni * 16 + lr;
            float bc = b_coarse[col];
            #pragma unroll
            for (int j = 0; j < 4; ++j) {
                int row = wm * 64 + mi * 16 + lrow4 + j;
                float v = acc1[mi][ni][j] + bc;
                acc1[mi][ni][j] = v;
                Xs[row * LDSP + col] = f32_to_bf16(v);
            }
        }
    }
    __syncthreads();

    floatx4 acc2[4][4];
    #pragma unroll
    for (int mi = 0; mi < 4; ++mi)
        #pragma unroll
        for (int ni = 0; ni < 4; ++ni)
            acc2[mi][ni] = (floatx4){0.f, 0.f, 0.f, 0.f};

    #pragma unroll
    for (int kk = 0; kk < 128; kk += 32) {
        short8 a[4], bb[4];
        #pragma unroll
        for (int mi = 0; mi < 4; ++mi)
            a[mi] = *(const short8*)(&Xs[(wm * 64 + mi * 16 + lr) * LDSP + kk + lk]);
        #pragma unroll
        for (int ni = 0; ni < 4; ++ni)
            bb[ni] = *(const short8*)(&Ws[(wn * 64 + ni * 16 + lr) * LDSP + kk + lk]);
        #pragma unroll
        for (int mi = 0; mi < 4; ++mi)
            #pragma unroll
            for (int ni = 0; ni < 4; ++ni)
                acc2[mi][ni] = __builtin_amdgcn_mfma_f32_16x16x32_bf16(a[mi], bb[ni], acc2[mi][ni], 0, 0, 0);
    }

    // epilogue: blend with gate, write f32
    #pragma unroll
    for (int mi = 0; mi < 4; ++mi) {
        #pragma unroll
        for (int ni = 0; ni < 4; ++ni) {
            int col = wn * 64 + ni * 16 + lr;
            float bf = b_fineout[col];
            #pragma unroll
            for (int j = 0; j < 4; ++j) {
                int row = wm * 64 + mi * 16 + lrow4 + j;
                int q = row0 + row;
                int b = q >> 14;              // / (128*128)
                int remq = q & 16383;
                int fy = remq >> 7, fx = remq & 127;
                float g = gate[(b << 12) + ((fy >> 1) << 6) + (fx >> 1)];
                float co = acc1[mi][ni][j];
                float fo = acc2[mi][ni][j] + bf;
                out[(size_t)q * FILTERS + col] = g * fo + (1.0f - g) * co;
            }
        }
    }
}

extern "C" void kernel_launch(void* const* d_in, const int* in_sizes, int n_in,
                              void* d_out, int out_size, void* d_ws, size_t ws_size,
                              hipStream_t stream) {
    const float* fine      = (const float*)d_in[0];
    const float* coarse    = (const float*)d_in[1];
    const float* w_gate    = (const float*)d_in[2];
    const float* b_gate    = (const float*)d_in[3];
    const float* w_sfine   = (const float*)d_in[4];
    const float* w_scoarse = (const float*)d_in[5];
    const float* b_scoarse = (const float*)d_in[6];
    const float* w_content = (const float*)d_in[7];
    const float* b_content = (const float*)d_in[8];
    const float* w_coarse  = (const float*)d_in[9];
    const float* b_coarse  = (const float*)d_in[10];
    const float* w_fineout = (const float*)d_in[11];
    const float* b_fineout = (const float*)d_in[12];
    float* out = (float*)d_out;

    const int B = 2, H = 128, W = 128, h = 64, w = 64;
    const int MF = B * H * W;   // 32768 fine pixels
    const int MC = B * h * w;   // 8192 coarse pixels

    char* ws = (char*)d_ws;
    size_t off = 0;
    auto alloc = [&](size_t bytes) {
        void* p = ws + off;
        off = (off + bytes + 255) & ~(size_t)255;
        return p;
    };
    float* g_gate   = (float*)alloc((size_t)MC * 4);
    float* f_emb    = (float*)alloc((size_t)MF * EMB * 4);
    float* c_emb    = (float*)alloc((size_t)MC * EMB * 4);
    float* f_conv   = (float*)alloc((size_t)MF * KK * 4);
    float* c_conv   = (float*)alloc((size_t)MC * KK * 4);
    unsigned short* x_bf16 = (unsigned short*)alloc((size_t)MF * CC * 2);
    unsigned short* wcT    = (unsigned short*)alloc(128 * 128 * 2);
    unsigned short* wfT    = (unsigned short*)alloc(128 * 128 * 2);

    // 1) gate
    gate_kernel<<<MC / 4, 256, 0, stream>>>(coarse, w_gate, b_gate, g_gate, MC);
    // 2) embeds
    embed_kernel<<<MF / 4, dim3(64, 4), 0, stream>>>(fine, w_sfine, nullptr, f_emb, MF, 128);
    embed_kernel<<<MC / 4, dim3(64, 4), 0, stream>>>(coarse, w_scoarse, b_scoarse, c_emb, MC, 128);
    // 3) content convs
    content_conv_kernel<<<MF / 64, 64, 0, stream>>>(f_emb, w_content, b_content, f_conv, H, W);
    content_conv_kernel<<<MC / 64, 64, 0, stream>>>(c_emb, w_content, b_content, c_conv, h, w);
    // 4) weight transposes (bf16)
    wtrans_kernel<<<64, 256, 0, stream>>>(w_coarse, wcT, 128 * 128);
    wtrans_kernel<<<64, 256, 0, stream>>>(w_fineout, wfT, 128 * 128);
    // 5) softmax + carafe
    carafe_kernel<<<MC, 256, 0, stream>>>(coarse, f_conv, c_conv, x_bf16, h, w);
    // 6) fused final GEMMs + blend
    final_kernel<<<MF / 128, 256, 0, stream>>>(x_bf16, wcT, wfT, b_coarse, b_fineout, g_gate, out);
}

// Round 2
// 90.462 us; speedup vs baseline: 3.6721x; 3.6721x over previous
//
#include <hip/hip_runtime.h>
#include <hip/hip_bf16.h>
#include <cstdint>
#include <cstddef>

#define KSZ 5
#define KK 25
#define EMB 64
#define CC 128
#define FILTERS 128

typedef __attribute__((ext_vector_type(8))) short short8;
typedef __attribute__((ext_vector_type(4))) float floatx4;

__device__ inline unsigned short f32_to_bf16(float f) {
    union { float f; unsigned u; } v; v.f = f;
    unsigned u = v.u;
    unsigned r = u + 0x7FFF + ((u >> 16) & 1);
    return (unsigned short)(r >> 16);
}

// ---------------- gate: sigmoid(coarse @ w_gate + b) at coarse res ----------------
__global__ void gate_kernel(const float* __restrict__ coarse,
                            const float* __restrict__ w_gate,
                            const float* __restrict__ b_gate,
                            float* __restrict__ gate, int npix) {
    int wave = (blockIdx.x * blockDim.x + threadIdx.x) >> 6;
    int lane = threadIdx.x & 63;
    if (wave >= npix) return;
    const float* src = coarse + (size_t)wave * CC;
    float acc = src[lane] * w_gate[lane] + src[lane + 64] * w_gate[lane + 64];
    #pragma unroll
    for (int off = 32; off > 0; off >>= 1)
        acc += __shfl_down(acc, off, 64);
    if (lane == 0) {
        float z = acc + b_gate[0];
        gate[wave] = 1.0f / (1.0f + __expf(-z));
    }
}

// ---------------- all weight transposes (f32 -> bf16, [K][N] -> [N][K]) ----------------
// sections: wsfT 64x128 (8192), wscT 64x128 (8192), wconT 32x576 (18432, zero-pad n>=25),
//           wcT 128x128 (16384), wfT 128x128 (16384). total 67584 = 264*256
__global__ void wtrans_all_kernel(const float* __restrict__ w_sfine,
                                  const float* __restrict__ w_scoarse,
                                  const float* __restrict__ w_content,
                                  const float* __restrict__ w_coarse,
                                  const float* __restrict__ w_fineout,
                                  unsigned short* __restrict__ wsfT,
                                  unsigned short* __restrict__ wscT,
                                  unsigned short* __restrict__ wconT,
                                  unsigned short* __restrict__ wcT,
                                  unsigned short* __restrict__ wfT) {
    int i = blockIdx.x * blockDim.x + threadIdx.x;
    if (i < 8192) {
        int n = i >> 7, k = i & 127;
        wsfT[i] = f32_to_bf16(w_sfine[k * 64 + n]);
    } else if (i < 16384) {
        int j = i - 8192;
        int n = j >> 7, k = j & 127;
        wscT[j] = f32_to_bf16(w_scoarse[k * 64 + n]);
    } else if (i < 34816) {
        int j = i - 16384;
        int n = j / 576, k = j - n * 576;
        float v = (n < 25) ? w_content[k * 25 + n] : 0.0f;
        wconT[j] = f32_to_bf16(v);
    } else if (i < 51200) {
        int j = i - 34816;
        int o = j >> 7, k = j & 127;
        wcT[j] = f32_to_bf16(w_coarse[k * 128 + o]);
    } else if (i < 67584) {
        int j = i - 51200;
        int o = j >> 7, k = j & 127;
        wfT[j] = f32_to_bf16(w_fineout[k * 128 + o]);
    }
}

// ---------------- embed MFMA: y[M,64](bf16) = x[M,128](f32) @ w[128,64], opt bias ----------------
#define XS_P 136
__global__ __launch_bounds__(256) void embed_mfma_kernel(
        const float* __restrict__ x,
        const unsigned short* __restrict__ wT,   // bf16 [64][128]
        const float* __restrict__ bias,          // [64] or null
        unsigned short* __restrict__ y) {        // bf16 [M][64]
    __shared__ unsigned short Xs[128 * XS_P];
    __shared__ unsigned short Ws[64 * XS_P];
    int tid = threadIdx.x;
    size_t row0 = (size_t)blockIdx.x * 128;

    {
        const float4* src = (const float4*)(x + row0 * 128);
        for (int ci = tid; ci < 4096; ci += 256) {
            int r = ci >> 5, c4 = ci & 31;
            float4 v = src[ci];
            uint2 u;
            u.x = (unsigned)f32_to_bf16(v.x) | ((unsigned)f32_to_bf16(v.y) << 16);
            u.y = (unsigned)f32_to_bf16(v.z) | ((unsigned)f32_to_bf16(v.w) << 16);
            *(uint2*)(&Xs[r * XS_P + c4 * 4]) = u;
        }
        const uint4* wsrc = (const uint4*)wT;
        for (int ci = tid; ci < 1024; ci += 256) {
            int n = ci >> 4, k8 = ci & 15;
            *(uint4*)(&Ws[n * XS_P + k8 * 8]) = wsrc[ci];
        }
    }
    __syncthreads();

    int wid = tid >> 6, lane = tid & 63;
    int lr = lane & 15, hi = lane >> 4, lk = hi * 8;

    floatx4 acc[2][4];
    #pragma unroll
    for (int mi = 0; mi < 2; ++mi)
        #pragma unroll
        for (int ni = 0; ni < 4; ++ni)
            acc[mi][ni] = (floatx4){0.f, 0.f, 0.f, 0.f};

    #pragma unroll
    for (int kk = 0; kk < 128; kk += 32) {
        short8 a[2], bb[4];
        #pragma unroll
        for (int mi = 0; mi < 2; ++mi)
            a[mi] = *(const short8*)(&Xs[(wid * 32 + mi * 16 + lr) * XS_P + kk + lk]);
        #pragma unroll
        for (int ni = 0; ni < 4; ++ni)
            bb[ni] = *(const short8*)(&Ws[(ni * 16 + lr) * XS_P + kk + lk]);
        #pragma unroll
        for (int mi = 0; mi < 2; ++mi)
            #pragma unroll
            for (int ni = 0; ni < 4; ++ni)
                acc[mi][ni] = __builtin_amdgcn_mfma_f32_16x16x32_bf16(a[mi], bb[ni], acc[mi][ni], 0, 0, 0);
    }

    #pragma unroll
    for (int mi = 0; mi < 2; ++mi) {
        #pragma unroll
        for (int ni = 0; ni < 4; ++ni) {
            int col = ni * 16 + lr;
            float bs = bias ? bias[col] : 0.0f;
            #pragma unroll
            for (int j = 0; j < 4; ++j) {
                int row = wid * 32 + mi * 16 + hi * 4 + j;
                y[(row0 + row) * EMB + col] = f32_to_bf16(acc[mi][ni][j] + bs);
            }
        }
    }
}

// ---------------- content conv MFMA (im2col): emb[B,Hh,Ww,64](bf16) -> y[B,Hh,Ww,25](f32) ----------------
// tile: 4 rows x 32 cols of pixels; halo 6x34; K = 9 taps * 64 emb = 576; N = 25 (padded 32)
#define SP 72
#define SB 584
__global__ __launch_bounds__(256) void content_mfma_kernel(
        const unsigned short* __restrict__ emb,
        const unsigned short* __restrict__ wT,   // bf16 [32][576]
        const float* __restrict__ bias,          // [25]
        float* __restrict__ y,
        int HT, int WT, int Hh, int Ww) {
    __shared__ unsigned short Es[6 * 34 * SP];   // 14688 elems
    __shared__ unsigned short Bs[32 * SB];       // 18688 elems
    int tid = threadIdx.x;
    int bx = blockIdx.x % WT;
    int t = blockIdx.x / WT;
    int by = t % HT;
    int b = t / HT;

    for (int ci = tid; ci < 1632; ci += 256) {   // 204 halo pixels * 8 chunks
        int pi = ci >> 3, e8 = ci & 7;
        int hy = pi / 34, hx = pi - hy * 34;
        int gy = by * 4 + hy - 1, gx = bx * 32 + hx - 1;
        uint4 v = {0u, 0u, 0u, 0u};
        if (gy >= 0 && gy < Hh && gx >= 0 && gx < Ww)
            v = *(const uint4*)(emb + (((size_t)(b * Hh + gy)) * Ww + gx) * EMB + e8 * 8);
        *(uint4*)(&Es[pi * SP + e8 * 8]) = v;
    }
    for (int ci = tid; ci < 2304; ci += 256) {   // 32 rows * 72 chunks
        int n = ci / 72, k8 = ci - n * 72;
        *(uint4*)(&Bs[n * SB + k8 * 8]) = *(const uint4*)(wT + n * 576 + k8 * 8);
    }
    __syncthreads();

    int wid = tid >> 6, lane = tid & 63;
    int lr = lane & 15, hi = lane >> 4, lk = hi * 8;

    floatx4 acc[2][2];
    #pragma unroll
    for (int mi = 0; mi < 2; ++mi)
        #pragma unroll
        for (int ni = 0; ni < 2; ++ni)
            acc[mi][ni] = (floatx4){0.f, 0.f, 0.f, 0.f};

    #pragma unroll
    for (int tap = 0; tap < 9; ++tap) {
        int dy = tap / 3, dx = tap - dy * 3;
        #pragma unroll
        for (int ks = 0; ks < 2; ++ks) {
            short8 a[2], bb[2];
            #pragma unroll
            for (int mi = 0; mi < 2; ++mi) {
                int p = wid * 32 + mi * 16 + lr;
                int r = p >> 5, c = p & 31;
                a[mi] = *(const short8*)(&Es[((r + dy) * 34 + (c + dx)) * SP + ks * 32 + lk]);
            }
            #pragma unroll
            for (int ni = 0; ni < 2; ++ni)
                bb[ni] = *(const short8*)(&Bs[(ni * 16 + lr) * SB + tap * 64 + ks * 32 + lk]);
            #pragma unroll
            for (int mi = 0; mi < 2; ++mi)
                #pragma unroll
                for (int ni = 0; ni < 2; ++ni)
                    acc[mi][ni] = __builtin_amdgcn_mfma_f32_16x16x32_bf16(a[mi], bb[ni], acc[mi][ni], 0, 0, 0);
        }
    }

    #pragma unroll
    for (int mi = 0; mi < 2; ++mi) {
        #pragma unroll
        for (int ni = 0; ni < 2; ++ni) {
            int n = ni * 16 + lr;
            if (n < KK) {
                float bs = bias[n];
                #pragma unroll
                for (int j = 0; j < 4; ++j) {
                    int p = wid * 32 + mi * 16 + hi * 4 + j;
                    int r = p >> 5, c = p & 31;
                    size_t gq = ((size_t)(b * Hh + by * 4 + r)) * Ww + bx * 32 + c;
                    y[gq * KK + n] = acc[mi][ni][j] + bs;
                }
            }
        }
    }
}

// ---------------- fused softmax + CARAFE (faithful reshape), out bf16 ----------------
__global__ void carafe_kernel(const float* __restrict__ coarse,  // [B,h,w,128]
                              const float* __restrict__ f_conv,  // [B,H,W,25]
                              const float* __restrict__ c_conv,  // [B,h,w,25]
                              unsigned short* __restrict__ xout, // bf16 [B,H,W,128]
                              int h, int w) {
    __shared__ float patch[KK * CC];
    int cpix = blockIdx.x;
    int npix_img = h * w;
    int b = cpix / npix_img;
    int rem = cpix - b * npix_img;
    int cy = rem / w;
    int cx = rem - cy * w;
    for (int i = threadIdx.x; i < KK * CC; i += blockDim.x) {
        int p = i >> 7, ch = i & 127;
        int py = cy + (p / KSZ) - 2, px = cx + (p % KSZ) - 2;
        float v = 0.0f;
        if (py >= 0 && py < h && px >= 0 && px < w)
            v = coarse[(((size_t)(b * h + py)) * w + px) * CC + ch];
        patch[i] = v;
    }
    __syncthreads();
    int wid = threadIdx.x >> 6;
    int lane = threadIdx.x & 63;
    int H = 2 * h, W = 2 * w;
    int fy = 2 * cy + (wid >> 1);
    int fx = 2 * cx + (wid & 1);
    size_t fq = ((size_t)(b * H + fy)) * W + fx;
    const float* fc = f_conv + fq * KK;
    const float* cc2 = c_conv + (size_t)cpix * KK;
    float lg[KK];
    float m = -1e30f;
    #pragma unroll
    for (int k = 0; k < KK; ++k) {
        lg[k] = fc[k] + cc2[k];
        m = fmaxf(m, lg[k]);
    }
    float s = 0.0f;
    #pragma unroll
    for (int k = 0; k < KK; ++k) {
        lg[k] = __expf(lg[k] - m);
        s += lg[k];
    }
    float inv = 1.0f / s;
    unsigned short* outp = xout + fq * CC;
    #pragma unroll
    for (int cp = 0; cp < 2; ++cp) {
        int c = lane + 64 * cp;
        const float* pp = patch + c * KK;
        float acc = 0.0f;
        #pragma unroll
        for (int k = 0; k < KK; ++k)
            acc += lg[k] * pp[k];
        outp[c] = f32_to_bf16(acc * inv);
    }
}

// ---------------- fused final: out = g*(co@Wf+bf) + (1-g)*co, co = X@Wc+bc ----------------
#define LDSP 136
__global__ __launch_bounds__(256) void final_kernel(
        const unsigned short* __restrict__ X,    // bf16 [M,128]
        const unsigned short* __restrict__ WcT,  // bf16 [o][k]
        const unsigned short* __restrict__ WfT,  // bf16 [p][o]
        const float* __restrict__ b_coarse,
        const float* __restrict__ b_fineout,
        const float* __restrict__ gate,          // [B*h*w]
        float* __restrict__ out) {
    __shared__ unsigned short Xs[128 * LDSP];
    __shared__ unsigned short Ws[128 * LDSP];
    int tid = threadIdx.x;
    int row0 = blockIdx.x * 128;

    {
        const uint4* src = (const uint4*)(X + (size_t)row0 * 128);
        const uint4* wsrc = (const uint4*)WcT;
        for (int ci = tid; ci < 2048; ci += 256) {
            int r = ci >> 4, c = ci & 15;
            *(uint4*)(&Xs[r * LDSP + c * 8]) = src[ci];
            *(uint4*)(&Ws[r * LDSP + c * 8]) = wsrc[ci];
        }
    }
    __syncthreads();

    int wid = tid >> 6, lane = tid & 63;
    int wm = wid >> 1, wn = wid & 1;
    int lr = lane & 15;
    int lk = (lane >> 4) * 8;
    int lrow4 = (lane >> 4) * 4;

    floatx4 acc1[4][4];
    #pragma unroll
    for (int mi = 0; mi < 4; ++mi)
        #pragma unroll
        for (int ni = 0; ni < 4; ++ni)
            acc1[mi][ni] = (floatx4){0.f, 0.f, 0.f, 0.f};

    #pragma unroll
    for (int kk = 0; kk < 128; kk += 32) {
        short8 a[4], bb[4];
        #pragma unroll
        for (int mi = 0; mi < 4; ++mi)
            a[mi] = *(const short8*)(&Xs[(wm * 64 + mi * 16 + lr) * LDSP + kk + lk]);
        #pragma unroll
        for (int ni = 0; ni < 4; ++ni)
            bb[ni] = *(const short8*)(&Ws[(wn * 64 + ni * 16 + lr) * LDSP + kk + lk]);
        #pragma unroll
        for (int mi = 0; mi < 4; ++mi)
            #pragma unroll
            for (int ni = 0; ni < 4; ++ni)
                acc1[mi][ni] = __builtin_amdgcn_mfma_f32_16x16x32_bf16(a[mi], bb[ni], acc1[mi][ni], 0, 0, 0);
    }
    __syncthreads();

    {
        const uint4* wsrc = (const uint4*)WfT;
        for (int ci = tid; ci < 2048; ci += 256) {
            int r = ci >> 4, c = ci & 15;
            *(uint4*)(&Ws[r * LDSP + c * 8]) = wsrc[ci];
        }
    }
    #pragma unroll
    for (int mi = 0; mi < 4; ++mi) {
        #pragma unroll
        for (int ni = 0; ni < 4; ++ni) {
            int col = wn * 64 + ni * 16 + lr;
            float bc = b_coarse[col];
            #pragma unroll
            for (int j = 0; j < 4; ++j) {
                int row = wm * 64 + mi * 16 + lrow4 + j;
                float v = acc1[mi][ni][j] + bc;
                acc1[mi][ni][j] = v;
                Xs[row * LDSP + col] = f32_to_bf16(v);
            }
        }
    }
    __syncthreads();

    floatx4 acc2[4][4];
    #pragma unroll
    for (int mi = 0; mi < 4; ++mi)
        #pragma unroll
        for (int ni = 0; ni < 4; ++ni)
            acc2[mi][ni] = (floatx4){0.f, 0.f, 0.f, 0.f};

    #pragma unroll
    for (int kk = 0; kk < 128; kk += 32) {
        short8 a[4], bb[4];
        #pragma unroll
        for (int mi = 0; mi < 4; ++mi)
            a[mi] = *(const short8*)(&Xs[(wm * 64 + mi * 16 + lr) * LDSP + kk + lk]);
        #pragma unroll
        for (int ni = 0; ni < 4; ++ni)
            bb[ni] = *(const short8*)(&Ws[(wn * 64 + ni * 16 + lr) * LDSP + kk + lk]);
        #pragma unroll
        for (int mi = 0; mi < 4; ++mi)
            #pragma unroll
            for (int ni = 0; ni < 4; ++ni)
                acc2[mi][ni] = __builtin_amdgcn_mfma_f32_16x16x32_bf16(a[mi], bb[ni], acc2[mi][ni], 0, 0, 0);
    }

    #pragma unroll
    for (int mi = 0; mi < 4; ++mi) {
        #pragma unroll
        for (int ni = 0; ni < 4; ++ni) {
            int col = wn * 64 + ni * 16 + lr;
            float bf = b_fineout[col];
            #pragma unroll
            for (int j = 0; j < 4; ++j) {
                int row = wm * 64 + mi * 16 + lrow4 + j;
                int q = row0 + row;
                int b = q >> 14;
                int remq = q & 16383;
                int fy = remq >> 7, fx = remq & 127;
                float g = gate[(b << 12) + ((fy >> 1) << 6) + (fx >> 1)];
                float co = acc1[mi][ni][j];
                float fo = acc2[mi][ni][j] + bf;
                out[(size_t)q * FILTERS + col] = g * fo + (1.0f - g) * co;
            }
        }
    }
}

extern "C" void kernel_launch(void* const* d_in, const int* in_sizes, int n_in,
                              void* d_out, int out_size, void* d_ws, size_t ws_size,
                              hipStream_t stream) {
    const float* fine      = (const float*)d_in[0];
    const float* coarse    = (const float*)d_in[1];
    const float* w_gate    = (const float*)d_in[2];
    const float* b_gate    = (const float*)d_in[3];
    const float* w_sfine   = (const float*)d_in[4];
    const float* w_scoarse = (const float*)d_in[5];
    const float* b_scoarse = (const float*)d_in[6];
    const float* w_content = (const float*)d_in[7];
    const float* b_content = (const float*)d_in[8];
    const float* w_coarse  = (const float*)d_in[9];
    const float* b_coarse  = (const float*)d_in[10];
    const float* w_fineout = (const float*)d_in[11];
    const float* b_fineout = (const float*)d_in[12];
    float* out = (float*)d_out;

    const int B = 2, H = 128, W = 128, h = 64, w = 64;
    const int MF = B * H * W;   // 32768
    const int MC = B * h * w;   // 8192

    char* ws = (char*)d_ws;
    size_t off = 0;
    auto alloc = [&](size_t bytes) {
        void* p = ws + off;
        off = (off + bytes + 255) & ~(size_t)255;
        return p;
    };
    float* g_gate            = (float*)alloc((size_t)MC * 4);
    unsigned short* f_emb    = (unsigned short*)alloc((size_t)MF * EMB * 2);
    unsigned short* c_emb    = (unsigned short*)alloc((size_t)MC * EMB * 2);
    float* f_conv            = (float*)alloc((size_t)MF * KK * 4);
    float* c_conv            = (float*)alloc((size_t)MC * KK * 4);
    unsigned short* x_bf16   = (unsigned short*)alloc((size_t)MF * CC * 2);
    unsigned short* wsfT     = (unsigned short*)alloc(64 * 128 * 2);
    unsigned short* wscT     = (unsigned short*)alloc(64 * 128 * 2);
    unsigned short* wconT    = (unsigned short*)alloc(32 * 576 * 2);
    unsigned short* wcT      = (unsigned short*)alloc(128 * 128 * 2);
    unsigned short* wfT      = (unsigned short*)alloc(128 * 128 * 2);

    gate_kernel<<<MC / 4, 256, 0, stream>>>(coarse, w_gate, b_gate, g_gate, MC);
    wtrans_all_kernel<<<264, 256, 0, stream>>>(w_sfine, w_scoarse, w_content, w_coarse, w_fineout,
                                               wsfT, wscT, wconT, wcT, wfT);
    embed_mfma_kernel<<<MF / 128, 256, 0, stream>>>(fine, wsfT, nullptr, f_emb);
    embed_mfma_kernel<<<MC / 128, 256, 0, stream>>>(coarse, wscT, b_scoarse, c_emb);
    content_mfma_kernel<<<B * (H / 4) * (W / 32), 256, 0, stream>>>(f_emb, wconT, b_content, f_conv, H / 4, W / 32, H, W);
    content_mfma_kernel<<<B * (h / 4) * (w / 32), 256, 0, stream>>>(c_emb, wconT, b_content, c_conv, h / 4, w / 32, h, w);
    carafe_kernel<<<MC, 256, 0, stream>>>(coarse, f_conv, c_conv, x_bf16, h, w);
    final_kernel<<<MF / 128, 256, 0, stream>>>(x_bf16, wcT, wfT, b_coarse, b_fineout, g_gate, out);
}

// Round 3
// 72.109 us; speedup vs baseline: 4.6067x; 1.2545x over previous
//
#include <hip/hip_runtime.h>
#include <hip/hip_bf16.h>
#include <cstdint>
#include <cstddef>

#define KSZ 5
#define KK 25
#define EMB 64
#define CC 128
#define FILTERS 128

typedef __attribute__((ext_vector_type(8))) short short8;
typedef __attribute__((ext_vector_type(4))) float floatx4;

__device__ inline unsigned short f32_to_bf16(float f) {
    union { float f; unsigned u; } v; v.f = f;
    unsigned u = v.u;
    unsigned r = u + 0x7FFF + ((u >> 16) & 1);
    return (unsigned short)(r >> 16);
}

// ---------------- gate: sigmoid(coarse @ w_gate + b) at coarse res ----------------
__global__ void gate_kernel(const float* __restrict__ coarse,
                            const float* __restrict__ w_gate,
                            const float* __restrict__ b_gate,
                            float* __restrict__ gate, int npix) {
    int wave = (blockIdx.x * blockDim.x + threadIdx.x) >> 6;
    int lane = threadIdx.x & 63;
    if (wave >= npix) return;
    const float* src = coarse + (size_t)wave * CC;
    float acc = src[lane] * w_gate[lane] + src[lane + 64] * w_gate[lane + 64];
    #pragma unroll
    for (int off = 32; off > 0; off >>= 1)
        acc += __shfl_down(acc, off, 64);
    if (lane == 0) {
        float z = acc + b_gate[0];
        gate[wave] = 1.0f / (1.0f + __expf(-z));
    }
}

// ---------------- all weight transposes (f32 -> bf16, [K][N] -> [N][K]) ----------------
__global__ void wtrans_all_kernel(const float* __restrict__ w_sfine,
                                  const float* __restrict__ w_scoarse,
                                  const float* __restrict__ w_content,
                                  const float* __restrict__ w_coarse,
                                  const float* __restrict__ w_fineout,
                                  unsigned short* __restrict__ wsfT,
                                  unsigned short* __restrict__ wscT,
                                  unsigned short* __restrict__ wconT,
                                  unsigned short* __restrict__ wcT,
                                  unsigned short* __restrict__ wfT) {
    int i = blockIdx.x * blockDim.x + threadIdx.x;
    if (i < 8192) {
        int n = i >> 7, k = i & 127;
        wsfT[i] = f32_to_bf16(w_sfine[k * 64 + n]);
    } else if (i < 16384) {
        int j = i - 8192;
        int n = j >> 7, k = j & 127;
        wscT[j] = f32_to_bf16(w_scoarse[k * 64 + n]);
    } else if (i < 34816) {
        int j = i - 16384;
        int n = j / 576, k = j - n * 576;
        float v = (n < 25) ? w_content[k * 25 + n] : 0.0f;
        wconT[j] = f32_to_bf16(v);
    } else if (i < 51200) {
        int j = i - 34816;
        int o = j >> 7, k = j & 127;
        wcT[j] = f32_to_bf16(w_coarse[k * 128 + o]);
    } else if (i < 67584) {
        int j = i - 51200;
        int o = j >> 7, k = j & 127;
        wfT[j] = f32_to_bf16(w_fineout[k * 128 + o]);
    }
}

// ---------------- embed MFMA: y[M,64](bf16) = x[M,128](f32) @ w[128,64], opt bias ----------------
#define XS_P 136
__global__ __launch_bounds__(256) void embed_mfma_kernel(
        const float* __restrict__ x,
        const unsigned short* __restrict__ wT,   // bf16 [64][128]
        const float* __restrict__ bias,          // [64] or null
        unsigned short* __restrict__ y) {        // bf16 [M][64]
    __shared__ unsigned short Xs[128 * XS_P];
    __shared__ unsigned short Ws[64 * XS_P];
    int tid = threadIdx.x;
    size_t row0 = (size_t)blockIdx.x * 128;

    {
        const float4* src = (const float4*)(x + row0 * 128);
        for (int ci = tid; ci < 4096; ci += 256) {
            int r = ci >> 5, c4 = ci & 31;
            float4 v = src[ci];
            uint2 u;
            u.x = (unsigned)f32_to_bf16(v.x) | ((unsigned)f32_to_bf16(v.y) << 16);
            u.y = (unsigned)f32_to_bf16(v.z) | ((unsigned)f32_to_bf16(v.w) << 16);
            *(uint2*)(&Xs[r * XS_P + c4 * 4]) = u;
        }
        const uint4* wsrc = (const uint4*)wT;
        for (int ci = tid; ci < 1024; ci += 256) {
            int n = ci >> 4, k8 = ci & 15;
            *(uint4*)(&Ws[n * XS_P + k8 * 8]) = wsrc[ci];
        }
    }
    __syncthreads();

    int wid = tid >> 6, lane = tid & 63;
    int lr = lane & 15, hi = lane >> 4, lk = hi * 8;

    floatx4 acc[2][4];
    #pragma unroll
    for (int mi = 0; mi < 2; ++mi)
        #pragma unroll
        for (int ni = 0; ni < 4; ++ni)
            acc[mi][ni] = (floatx4){0.f, 0.f, 0.f, 0.f};

    #pragma unroll
    for (int kk = 0; kk < 128; kk += 32) {
        short8 a[2], bb[4];
        #pragma unroll
        for (int mi = 0; mi < 2; ++mi)
            a[mi] = *(const short8*)(&Xs[(wid * 32 + mi * 16 + lr) * XS_P + kk + lk]);
        #pragma unroll
        for (int ni = 0; ni < 4; ++ni)
            bb[ni] = *(const short8*)(&Ws[(ni * 16 + lr) * XS_P + kk + lk]);
        #pragma unroll
        for (int mi = 0; mi < 2; ++mi)
            #pragma unroll
            for (int ni = 0; ni < 4; ++ni)
                acc[mi][ni] = __builtin_amdgcn_mfma_f32_16x16x32_bf16(a[mi], bb[ni], acc[mi][ni], 0, 0, 0);
    }

    #pragma unroll
    for (int mi = 0; mi < 2; ++mi) {
        #pragma unroll
        for (int ni = 0; ni < 4; ++ni) {
            int col = ni * 16 + lr;
            float bs = bias ? bias[col] : 0.0f;
            #pragma unroll
            for (int j = 0; j < 4; ++j) {
                int row = wid * 32 + mi * 16 + hi * 4 + j;
                y[(row0 + row) * EMB + col] = f32_to_bf16(acc[mi][ni][j] + bs);
            }
        }
    }
}

// ---------------- content conv MFMA (im2col): emb[B,Hh,Ww,64](bf16) -> y[B,Hh,Ww,25](f32) ----------------
#define SP 72
#define SB 584
__global__ __launch_bounds__(256) void content_mfma_kernel(
        const unsigned short* __restrict__ emb,
        const unsigned short* __restrict__ wT,   // bf16 [32][576]
        const float* __restrict__ bias,          // [25]
        float* __restrict__ y,
        int HT, int WT, int Hh, int Ww) {
    __shared__ unsigned short Es[6 * 34 * SP];
    __shared__ unsigned short Bs[32 * SB];
    int tid = threadIdx.x;
    int bx = blockIdx.x % WT;
    int t = blockIdx.x / WT;
    int by = t % HT;
    int b = t / HT;

    for (int ci = tid; ci < 1632; ci += 256) {
        int pi = ci >> 3, e8 = ci & 7;
        int hy = pi / 34, hx = pi - hy * 34;
        int gy = by * 4 + hy - 1, gx = bx * 32 + hx - 1;
        uint4 v = {0u, 0u, 0u, 0u};
        if (gy >= 0 && gy < Hh && gx >= 0 && gx < Ww)
            v = *(const uint4*)(emb + (((size_t)(b * Hh + gy)) * Ww + gx) * EMB + e8 * 8);
        *(uint4*)(&Es[pi * SP + e8 * 8]) = v;
    }
    for (int ci = tid; ci < 2304; ci += 256) {
        int n = ci / 72, k8 = ci - n * 72;
        *(uint4*)(&Bs[n * SB + k8 * 8]) = *(const uint4*)(wT + n * 576 + k8 * 8);
    }
    __syncthreads();

    int wid = tid >> 6, lane = tid & 63;
    int lr = lane & 15, hi = lane >> 4, lk = hi * 8;

    floatx4 acc[2][2];
    #pragma unroll
    for (int mi = 0; mi < 2; ++mi)
        #pragma unroll
        for (int ni = 0; ni < 2; ++ni)
            acc[mi][ni] = (floatx4){0.f, 0.f, 0.f, 0.f};

    #pragma unroll
    for (int tap = 0; tap < 9; ++tap) {
        int dy = tap / 3, dx = tap - dy * 3;
        #pragma unroll
        for (int ks = 0; ks < 2; ++ks) {
            short8 a[2], bb[2];
            #pragma unroll
            for (int mi = 0; mi < 2; ++mi) {
                int p = wid * 32 + mi * 16 + lr;
                int r = p >> 5, c = p & 31;
                a[mi] = *(const short8*)(&Es[((r + dy) * 34 + (c + dx)) * SP + ks * 32 + lk]);
            }
            #pragma unroll
            for (int ni = 0; ni < 2; ++ni)
                bb[ni] = *(const short8*)(&Bs[(ni * 16 + lr) * SB + tap * 64 + ks * 32 + lk]);
            #pragma unroll
            for (int mi = 0; mi < 2; ++mi)
                #pragma unroll
                for (int ni = 0; ni < 2; ++ni)
                    acc[mi][ni] = __builtin_amdgcn_mfma_f32_16x16x32_bf16(a[mi], bb[ni], acc[mi][ni], 0, 0, 0);
        }
    }

    #pragma unroll
    for (int mi = 0; mi < 2; ++mi) {
        #pragma unroll
        for (int ni = 0; ni < 2; ++ni) {
            int n = ni * 16 + lr;
            if (n < KK) {
                float bs = bias[n];
                #pragma unroll
                for (int j = 0; j < 4; ++j) {
                    int p = wid * 32 + mi * 16 + hi * 4 + j;
                    int r = p >> 5, c = p & 31;
                    size_t gq = ((size_t)(b * Hh + by * 4 + r)) * Ww + bx * 32 + c;
                    y[gq * KK + n] = acc[mi][ni][j] + bs;
                }
            }
        }
    }
}

// ---------------- fused softmax + CARAFE (faithful reshape), out bf16 ----------------
// one block per coarse pixel, 4 waves = 4 fine pixels. Wave-parallel softmax,
// register-cached weights, immediate-offset LDS gather.
__global__ __launch_bounds__(256) void carafe_kernel(
        const float* __restrict__ coarse,  // [B,h,w,128]
        const float* __restrict__ f_conv,  // [B,H,W,25]
        const float* __restrict__ c_conv,  // [B,h,w,25]
        unsigned short* __restrict__ xout, // bf16 [B,H,W,128]
        int h, int w) {
    __shared__ float patch[KK * CC];   // flat faithful [k*128+c], 12.8 KB
    __shared__ float wsm[4 * 32];      // per-wave normalized weights (pad to 32)
    int cpix = blockIdx.x;
    int npix = h * w;
    int b = cpix / npix;
    int rem = cpix - b * npix;
    int cy = rem / w;
    int cx = rem - cy * w;
    int tid = threadIdx.x;

    // Phase A: stage patch as float4 (800 vec4 loads)
    for (int ci = tid; ci < 800; ci += 256) {
        int k = ci >> 5;                 // tap position 0..24
        int c4 = (ci & 31) << 2;         // channel 0,4,...,124
        int dy = (k * 205) >> 10;        // k/5 for k<32
        int dx = k - dy * 5;
        int py = cy + dy - 2, px = cx + dx - 2;
        float4 v = {0.f, 0.f, 0.f, 0.f};
        if (py >= 0 && py < h && px >= 0 && px < w)
            v = *(const float4*)(coarse + (((size_t)(b * h + py)) * w + px) * CC + c4);
        *(float4*)(&patch[ci << 2]) = v;
    }

    // Phase B: wave-parallel softmax (lane k handles tap k)
    int wid = tid >> 6, lane = tid & 63;
    int fy = 2 * cy + (wid >> 1);
    int fx = 2 * cx + (wid & 1);
    int H2 = 2 * h, W2 = 2 * w;
    size_t fq = ((size_t)(b * H2 + fy)) * W2 + fx;
    {
        int k = lane & 31;
        float v = -1e30f;
        if (k < KK)
            v = f_conv[fq * KK + k] + c_conv[(size_t)cpix * KK + k];
        float m = v;
        #pragma unroll
        for (int mask = 16; mask > 0; mask >>= 1)
            m = fmaxf(m, __shfl_xor(m, mask, 32));
        float e = (k < KK) ? __expf(v - m) : 0.0f;
        float s = e;
        #pragma unroll
        for (int mask = 16; mask > 0; mask >>= 1)
            s += __shfl_xor(s, mask, 32);
        if (lane < 32)
            wsm[wid * 32 + k] = e / s;   // lanes 25..31 write 0
    }
    __syncthreads();

    // Phase C: gather. Weights into registers via broadcast b128 reads.
    float wreg[28];
    #pragma unroll
    for (int j4 = 0; j4 < 7; ++j4)
        *(float4*)(&wreg[j4 * 4]) = *(const float4*)(&wsm[wid * 32 + j4 * 4]);

    unsigned short* outp = xout + fq * CC;
    #pragma unroll
    for (int cp = 0; cp < 2; ++cp) {
        int c = lane + 64 * cp;
        const float* pp = patch + c * KK;   // contiguous 25 floats, imm offsets
        float acc = 0.0f;
        #pragma unroll
        for (int j = 0; j < KK; ++j)
            acc += wreg[j] * pp[j];
        outp[c] = f32_to_bf16(acc);
    }
}

// ---------------- fused final: out = g*(co@Wf+bf) + (1-g)*co, co = X@Wc+bc ----------------
#define LDSP 136
__global__ __launch_bounds__(256) void final_kernel(
        const unsigned short* __restrict__ X,    // bf16 [M,128]
        const unsigned short* __restrict__ WcT,  // bf16 [o][k]
        const unsigned short* __restrict__ WfT,  // bf16 [p][o]
        const float* __restrict__ b_coarse,
        const float* __restrict__ b_fineout,
        const float* __restrict__ gate,          // [B*h*w]
        float* __restrict__ out) {
    __shared__ unsigned short Xs[128 * LDSP];
    __shared__ unsigned short Ws[128 * LDSP];
    int tid = threadIdx.x;
    int row0 = blockIdx.x * 128;

    {
        const uint4* src = (const uint4*)(X + (size_t)row0 * 128);
        const uint4* wsrc = (const uint4*)WcT;
        for (int ci = tid; ci < 2048; ci += 256) {
            int r = ci >> 4, c = ci & 15;
            *(uint4*)(&Xs[r * LDSP + c * 8]) = src[ci];
            *(uint4*)(&Ws[r * LDSP + c * 8]) = wsrc[ci];
        }
    }
    __syncthreads();

    int wid = tid >> 6, lane = tid & 63;
    int wm = wid >> 1, wn = wid & 1;
    int lr = lane & 15;
    int lk = (lane >> 4) * 8;
    int lrow4 = (lane >> 4) * 4;

    floatx4 acc1[4][4];
    #pragma unroll
    for (int mi = 0; mi < 4; ++mi)
        #pragma unroll
        for (int ni = 0; ni < 4; ++ni)
            acc1[mi][ni] = (floatx4){0.f, 0.f, 0.f, 0.f};

    #pragma unroll
    for (int kk = 0; kk < 128; kk += 32) {
        short8 a[4], bb[4];
        #pragma unroll
        for (int mi = 0; mi < 4; ++mi)
            a[mi] = *(const short8*)(&Xs[(wm * 64 + mi * 16 + lr) * LDSP + kk + lk]);
        #pragma unroll
        for (int ni = 0; ni < 4; ++ni)
            bb[ni] = *(const short8*)(&Ws[(wn * 64 + ni * 16 + lr) * LDSP + kk + lk]);
        #pragma unroll
        for (int mi = 0; mi < 4; ++mi)
            #pragma unroll
            for (int ni = 0; ni < 4; ++ni)
                acc1[mi][ni] = __builtin_amdgcn_mfma_f32_16x16x32_bf16(a[mi], bb[ni], acc1[mi][ni], 0, 0, 0);
    }
    __syncthreads();

    {
        const uint4* wsrc = (const uint4*)WfT;
        for (int ci = tid; ci < 2048; ci += 256) {
            int r = ci >> 4, c = ci & 15;
            *(uint4*)(&Ws[r * LDSP + c * 8]) = wsrc[ci];
        }
    }
    #pragma unroll
    for (int mi = 0; mi < 4; ++mi) {
        #pragma unroll
        for (int ni = 0; ni < 4; ++ni) {
            int col = wn * 64 + ni * 16 + lr;
            float bc = b_coarse[col];
            #pragma unroll
            for (int j = 0; j < 4; ++j) {
                int row = wm * 64 + mi * 16 + lrow4 + j;
                float v = acc1[mi][ni][j] + bc;
                acc1[mi][ni][j] = v;
                Xs[row * LDSP + col] = f32_to_bf16(v);
            }
        }
    }
    __syncthreads();

    floatx4 acc2[4][4];
    #pragma unroll
    for (int mi = 0; mi < 4; ++mi)
        #pragma unroll
        for (int ni = 0; ni < 4; ++ni)
            acc2[mi][ni] = (floatx4){0.f, 0.f, 0.f, 0.f};

    #pragma unroll
    for (int kk = 0; kk < 128; kk += 32) {
        short8 a[4], bb[4];
        #pragma unroll
        for (int mi = 0; mi < 4; ++mi)
            a[mi] = *(const short8*)(&Xs[(wm * 64 + mi * 16 + lr) * LDSP + kk + lk]);
        #pragma unroll
        for (int ni = 0; ni < 4; ++ni)
            bb[ni] = *(const short8*)(&Ws[(wn * 64 + ni * 16 + lr) * LDSP + kk + lk]);
        #pragma unroll
        for (int mi = 0; mi < 4; ++mi)
            #pragma unroll
            for (int ni = 0; ni < 4; ++ni)
                acc2[mi][ni] = __builtin_amdgcn_mfma_f32_16x16x32_bf16(a[mi], bb[ni], acc2[mi][ni], 0, 0, 0);
    }

    #pragma unroll
    for (int mi = 0; mi < 4; ++mi) {
        #pragma unroll
        for (int ni = 0; ni < 4; ++ni) {
            int col = wn * 64 + ni * 16 + lr;
            float bf = b_fineout[col];
            #pragma unroll
            for (int j = 0; j < 4; ++j) {
                int row = wm * 64 + mi * 16 + lrow4 + j;
                int q = row0 + row;
                int b = q >> 14;
                int remq = q & 16383;
                int fy = remq >> 7, fx = remq & 127;
                float g = gate[(b << 12) + ((fy >> 1) << 6) + (fx >> 1)];
                float co = acc1[mi][ni][j];
                float fo = acc2[mi][ni][j] + bf;
                out[(size_t)q * FILTERS + col] = g * fo + (1.0f - g) * co;
            }
        }
    }
}

extern "C" void kernel_launch(void* const* d_in, const int* in_sizes, int n_in,
                              void* d_out, int out_size, void* d_ws, size_t ws_size,
                              hipStream_t stream) {
    const float* fine      = (const float*)d_in[0];
    const float* coarse    = (const float*)d_in[1];
    const float* w_gate    = (const float*)d_in[2];
    const float* b_gate    = (const float*)d_in[3];
    const float* w_sfine   = (const float*)d_in[4];
    const float* w_scoarse = (const float*)d_in[5];
    const float* b_scoarse = (const float*)d_in[6];
    const float* w_content = (const float*)d_in[7];
    const float* b_content = (const float*)d_in[8];
    const float* w_coarse  = (const float*)d_in[9];
    const float* b_coarse  = (const float*)d_in[10];
    const float* w_fineout = (const float*)d_in[11];
    const float* b_fineout = (const float*)d_in[12];
    float* out = (float*)d_out;

    const int B = 2, H = 128, W = 128, h = 64, w = 64;
    const int MF = B * H * W;   // 32768
    const int MC = B * h * w;   // 8192

    char* ws = (char*)d_ws;
    size_t off = 0;
    auto alloc = [&](size_t bytes) {
        void* p = ws + off;
        off = (off + bytes + 255) & ~(size_t)255;
        return p;
    };
    float* g_gate            = (float*)alloc((size_t)MC * 4);
    unsigned short* f_emb    = (unsigned short*)alloc((size_t)MF * EMB * 2);
    unsigned short* c_emb    = (unsigned short*)alloc((size_t)MC * EMB * 2);
    float* f_conv            = (float*)alloc((size_t)MF * KK * 4);
    float* c_conv            = (float*)alloc((size_t)MC * KK * 4);
    unsigned short* x_bf16   = (unsigned short*)alloc((size_t)MF * CC * 2);
    unsigned short* wsfT     = (unsigned short*)alloc(64 * 128 * 2);
    unsigned short* wscT     = (unsigned short*)alloc(64 * 128 * 2);
    unsigned short* wconT    = (unsigned short*)alloc(32 * 576 * 2);
    unsigned short* wcT      = (unsigned short*)alloc(128 * 128 * 2);
    unsigned short* wfT      = (unsigned short*)alloc(128 * 128 * 2);

    gate_kernel<<<MC / 4, 256, 0, stream>>>(coarse, w_gate, b_gate, g_gate, MC);
    wtrans_all_kernel<<<264, 256, 0, stream>>>(w_sfine, w_scoarse, w_content, w_coarse, w_fineout,
                                               wsfT, wscT, wconT, wcT, wfT);
    embed_mfma_kernel<<<MF / 128, 256, 0, stream>>>(fine, wsfT, nullptr, f_emb);
    embed_mfma_kernel<<<MC / 128, 256, 0, stream>>>(coarse, wscT, b_scoarse, c_emb);
    content_mfma_kernel<<<B * (H / 4) * (W / 32), 256, 0, stream>>>(f_emb, wconT, b_content, f_conv, H / 4, W / 32, H, W);
    content_mfma_kernel<<<B * (h / 4) * (w / 32), 256, 0, stream>>>(c_emb, wconT, b_content, c_conv, h / 4, w / 32, h, w);
    carafe_kernel<<<MC, 256, 0, stream>>>(coarse, f_conv, c_conv, x_bf16, h, w);
    final_kernel<<<MF / 128, 256, 0, stream>>>(x_bf16, wcT, wfT, b_coarse, b_fineout, g_gate, out);
}

// Round 4
// 58.031 us; speedup vs baseline: 5.7243x; 1.2426x over previous
//
#include <hip/hip_runtime.h>
#include <hip/hip_bf16.h>
#include <cstdint>
#include <cstddef>

#define KSZ 5
#define KK 25
#define EMB 64
#define CC 128
#define FILTERS 128

typedef __attribute__((ext_vector_type(8))) short short8;
typedef __attribute__((ext_vector_type(4))) float floatx4;

__device__ inline unsigned short f32_to_bf16(float f) {
    union { float f; unsigned u; } v; v.f = f;
    unsigned u = v.u;
    unsigned r = u + 0x7FFF + ((u >> 16) & 1);
    return (unsigned short)(r >> 16);
}

// ---------------- all weight transposes (f32 -> bf16, [K][N] -> [N][K]) ----------------
__global__ void wtrans_all_kernel(const float* __restrict__ w_sfine,
                                  const float* __restrict__ w_scoarse,
                                  const float* __restrict__ w_content,
                                  const float* __restrict__ w_coarse,
                                  const float* __restrict__ w_fineout,
                                  unsigned short* __restrict__ wsfT,
                                  unsigned short* __restrict__ wscT,
                                  unsigned short* __restrict__ wconT,
                                  unsigned short* __restrict__ wcT,
                                  unsigned short* __restrict__ wfT) {
    int i = blockIdx.x * blockDim.x + threadIdx.x;
    if (i < 8192) {
        int n = i >> 7, k = i & 127;
        wsfT[i] = f32_to_bf16(w_sfine[k * 64 + n]);
    } else if (i < 16384) {
        int j = i - 8192;
        int n = j >> 7, k = j & 127;
        wscT[j] = f32_to_bf16(w_scoarse[k * 64 + n]);
    } else if (i < 34816) {
        int j = i - 16384;
        int n = j / 576, k = j - n * 576;
        float v = (n < 25) ? w_content[k * 25 + n] : 0.0f;
        wconT[j] = f32_to_bf16(v);
    } else if (i < 51200) {
        int j = i - 34816;
        int o = j >> 7, k = j & 127;
        wcT[j] = f32_to_bf16(w_coarse[k * 128 + o]);
    } else if (i < 67584) {
        int j = i - 51200;
        int o = j >> 7, k = j & 127;
        wfT[j] = f32_to_bf16(w_fineout[k * 128 + o]);
    }
}

// ---------------- embed MFMA (both inputs in one grid) ----------------
// blocks [0, nf): fine rows;  [nf, nf+nc): coarse rows
#define XS_P 136
__global__ __launch_bounds__(256) void embed_both_kernel(
        const float* __restrict__ xf, const unsigned short* __restrict__ wTf,
        const float* __restrict__ xc, const unsigned short* __restrict__ wTc,
        const float* __restrict__ bias_c,
        unsigned short* __restrict__ yf, unsigned short* __restrict__ yc,
        int nf) {
    __shared__ unsigned short Xs[128 * XS_P];
    __shared__ unsigned short Ws[64 * XS_P];
    int tid = threadIdx.x;
    bool is_f = (int)blockIdx.x < nf;
    int blk = is_f ? blockIdx.x : (blockIdx.x - nf);
    const float* x = is_f ? xf : xc;
    const unsigned short* wT = is_f ? wTf : wTc;
    const float* bias = is_f ? nullptr : bias_c;
    unsigned short* y = is_f ? yf : yc;
    size_t row0 = (size_t)blk * 128;

    {
        const float4* src = (const float4*)(x + row0 * 128);
        for (int ci = tid; ci < 4096; ci += 256) {
            int r = ci >> 5, c4 = ci & 31;
            float4 v = src[ci];
            uint2 u;
            u.x = (unsigned)f32_to_bf16(v.x) | ((unsigned)f32_to_bf16(v.y) << 16);
            u.y = (unsigned)f32_to_bf16(v.z) | ((unsigned)f32_to_bf16(v.w) << 16);
            *(uint2*)(&Xs[r * XS_P + c4 * 4]) = u;
        }
        const uint4* wsrc = (const uint4*)wT;
        for (int ci = tid; ci < 1024; ci += 256) {
            int n = ci >> 4, k8 = ci & 15;
            *(uint4*)(&Ws[n * XS_P + k8 * 8]) = wsrc[ci];
        }
    }
    __syncthreads();

    int wid = tid >> 6, lane = tid & 63;
    int lr = lane & 15, hi = lane >> 4, lk = hi * 8;

    floatx4 acc[2][4];
    #pragma unroll
    for (int mi = 0; mi < 2; ++mi)
        #pragma unroll
        for (int ni = 0; ni < 4; ++ni)
            acc[mi][ni] = (floatx4){0.f, 0.f, 0.f, 0.f};

    #pragma unroll
    for (int kk = 0; kk < 128; kk += 32) {
        short8 a[2], bb[4];
        #pragma unroll
        for (int mi = 0; mi < 2; ++mi)
            a[mi] = *(const short8*)(&Xs[(wid * 32 + mi * 16 + lr) * XS_P + kk + lk]);
        #pragma unroll
        for (int ni = 0; ni < 4; ++ni)
            bb[ni] = *(const short8*)(&Ws[(ni * 16 + lr) * XS_P + kk + lk]);
        #pragma unroll
        for (int mi = 0; mi < 2; ++mi)
            #pragma unroll
            for (int ni = 0; ni < 4; ++ni)
                acc[mi][ni] = __builtin_amdgcn_mfma_f32_16x16x32_bf16(a[mi], bb[ni], acc[mi][ni], 0, 0, 0);
    }

    #pragma unroll
    for (int mi = 0; mi < 2; ++mi) {
        #pragma unroll
        for (int ni = 0; ni < 4; ++ni) {
            int col = ni * 16 + lr;
            float bs = bias ? bias[col] : 0.0f;
            #pragma unroll
            for (int j = 0; j < 4; ++j) {
                int row = wid * 32 + mi * 16 + hi * 4 + j;
                y[(row0 + row) * EMB + col] = f32_to_bf16(acc[mi][ni][j] + bs);
            }
        }
    }
}

// ---------------- content conv MFMA (both resolutions in one grid) ----------------
#define SP 72
#define SB 584
__global__ __launch_bounds__(256) void content_both_kernel(
        const unsigned short* __restrict__ embf,
        const unsigned short* __restrict__ embc,
        const unsigned short* __restrict__ wT,   // bf16 [32][576]
        const float* __restrict__ bias,          // [25]
        float* __restrict__ yf, float* __restrict__ yc,
        int nf) {
    __shared__ unsigned short Es[6 * 34 * SP];
    __shared__ unsigned short Bs[32 * SB];
    int tid = threadIdx.x;
    bool is_f = (int)blockIdx.x < nf;
    int blk = is_f ? blockIdx.x : (blockIdx.x - nf);
    const unsigned short* emb = is_f ? embf : embc;
    float* y = is_f ? yf : yc;
    int HT = is_f ? 32 : 16;   // H/4
    int WT = is_f ? 4 : 2;     // W/32
    int Hh = is_f ? 128 : 64;
    int Ww = is_f ? 128 : 64;

    int bx = blk % WT;
    int t = blk / WT;
    int by = t % HT;
    int b = t / HT;

    for (int ci = tid; ci < 1632; ci += 256) {
        int pi = ci >> 3, e8 = ci & 7;
        int hy = pi / 34, hx = pi - hy * 34;
        int gy = by * 4 + hy - 1, gx = bx * 32 + hx - 1;
        uint4 v = {0u, 0u, 0u, 0u};
        if (gy >= 0 && gy < Hh && gx >= 0 && gx < Ww)
            v = *(const uint4*)(emb + (((size_t)(b * Hh + gy)) * Ww + gx) * EMB + e8 * 8);
        *(uint4*)(&Es[pi * SP + e8 * 8]) = v;
    }
    for (int ci = tid; ci < 2304; ci += 256) {
        int n = ci / 72, k8 = ci - n * 72;
        *(uint4*)(&Bs[n * SB + k8 * 8]) = *(const uint4*)(wT + n * 576 + k8 * 8);
    }
    __syncthreads();

    int wid = tid >> 6, lane = tid & 63;
    int lr = lane & 15, hi = lane >> 4, lk = hi * 8;

    floatx4 acc[2][2];
    #pragma unroll
    for (int mi = 0; mi < 2; ++mi)
        #pragma unroll
        for (int ni = 0; ni < 2; ++ni)
            acc[mi][ni] = (floatx4){0.f, 0.f, 0.f, 0.f};

    #pragma unroll
    for (int tap = 0; tap < 9; ++tap) {
        int dy = tap / 3, dx = tap - dy * 3;
        #pragma unroll
        for (int ks = 0; ks < 2; ++ks) {
            short8 a[2], bb[2];
            #pragma unroll
            for (int mi = 0; mi < 2; ++mi) {
                int p = wid * 32 + mi * 16 + lr;
                int r = p >> 5, c = p & 31;
                a[mi] = *(const short8*)(&Es[((r + dy) * 34 + (c + dx)) * SP + ks * 32 + lk]);
            }
            #pragma unroll
            for (int ni = 0; ni < 2; ++ni)
                bb[ni] = *(const short8*)(&Bs[(ni * 16 + lr) * SB + tap * 64 + ks * 32 + lk]);
            #pragma unroll
            for (int mi = 0; mi < 2; ++mi)
                #pragma unroll
                for (int ni = 0; ni < 2; ++ni)
                    acc[mi][ni] = __builtin_amdgcn_mfma_f32_16x16x32_bf16(a[mi], bb[ni], acc[mi][ni], 0, 0, 0);
        }
    }

    #pragma unroll
    for (int mi = 0; mi < 2; ++mi) {
        #pragma unroll
        for (int ni = 0; ni < 2; ++ni) {
            int n = ni * 16 + lr;
            if (n < KK) {
                float bs = bias[n];
                #pragma unroll
                for (int j = 0; j < 4; ++j) {
                    int p = wid * 32 + mi * 16 + hi * 4 + j;
                    int r = p >> 5, c = p & 31;
                    size_t gq = ((size_t)(b * Hh + by * 4 + r)) * Ww + bx * 32 + c;
                    y[gq * KK + n] = acc[mi][ni][j] + bs;
                }
            }
        }
    }
}

// ---------------- fused softmax + CARAFE + gate ----------------
// one block per coarse pixel, 4 waves = 4 fine pixels.
__global__ __launch_bounds__(256) void carafe_gate_kernel(
        const float* __restrict__ coarse,  // [B,h,w,128]
        const float* __restrict__ f_conv,  // [B,H,W,25]
        const float* __restrict__ c_conv,  // [B,h,w,25]
        const float* __restrict__ w_gate,  // [128]
        const float* __restrict__ b_gate,  // [1]
        unsigned short* __restrict__ xout, // bf16 [B,H,W,128]
        float* __restrict__ g_gate,        // [B*h*w]
        int h, int w) {
    __shared__ float patch[KK * CC];   // flat faithful [pos*128+ch], 12.8 KB
    __shared__ float wsm[4 * 32];
    int cpix = blockIdx.x;
    int npix = h * w;
    int b = cpix / npix;
    int rem = cpix - b * npix;
    int cy = rem / w;
    int cx = rem - cy * w;
    int tid = threadIdx.x;

    // Phase A: stage patch as float4
    for (int ci = tid; ci < 800; ci += 256) {
        int k = ci >> 5;
        int c4 = (ci & 31) << 2;
        int dy = (k * 205) >> 10;
        int dx = k - dy * 5;
        int py = cy + dy - 2, px = cx + dx - 2;
        float4 v = {0.f, 0.f, 0.f, 0.f};
        if (py >= 0 && py < h && px >= 0 && px < w)
            v = *(const float4*)(coarse + (((size_t)(b * h + py)) * w + px) * CC + c4);
        *(float4*)(&patch[ci << 2]) = v;
    }

    // Phase B: wave-parallel softmax
    int wid = tid >> 6, lane = tid & 63;
    int fy = 2 * cy + (wid >> 1);
    int fx = 2 * cx + (wid & 1);
    int H2 = 2 * h, W2 = 2 * w;
    size_t fq = ((size_t)(b * H2 + fy)) * W2 + fx;
    {
        int k = lane & 31;
        float v = -1e30f;
        if (k < KK)
            v = f_conv[fq * KK + k] + c_conv[(size_t)cpix * KK + k];
        float m = v;
        #pragma unroll
        for (int mask = 16; mask > 0; mask >>= 1)
            m = fmaxf(m, __shfl_xor(m, mask, 32));
        float e = (k < KK) ? __expf(v - m) : 0.0f;
        float s = e;
        #pragma unroll
        for (int mask = 16; mask > 0; mask >>= 1)
            s += __shfl_xor(s, mask, 32);
        if (lane < 32)
            wsm[wid * 32 + k] = e / s;
    }
    __syncthreads();

    // gate from staged center pixel (tap 12) — identical f32 values as gate conv
    if (wid == 0) {
        float acc = patch[12 * CC + lane] * w_gate[lane]
                  + patch[12 * CC + lane + 64] * w_gate[lane + 64];
        #pragma unroll
        for (int off = 32; off > 0; off >>= 1)
            acc += __shfl_down(acc, off, 64);
        if (lane == 0) {
            float z = acc + b_gate[0];
            g_gate[cpix] = 1.0f / (1.0f + __expf(-z));
        }
    }

    // Phase C: gather
    float wreg[28];
    #pragma unroll
    for (int j4 = 0; j4 < 7; ++j4)
        *(float4*)(&wreg[j4 * 4]) = *(const float4*)(&wsm[wid * 32 + j4 * 4]);

    unsigned short* outp = xout + fq * CC;
    #pragma unroll
    for (int cp = 0; cp < 2; ++cp) {
        int c = lane + 64 * cp;
        const float* pp = patch + c * KK;
        float acc = 0.0f;
        #pragma unroll
        for (int j = 0; j < KK; ++j)
            acc += wreg[j] * pp[j];
        outp[c] = f32_to_bf16(acc);
    }
}

// ---------------- fused final (M=64 tiles): out = g*(co@Wf+bf) + (1-g)*co ----------------
#define LDSP 136
__global__ __launch_bounds__(256) void final_kernel(
        const unsigned short* __restrict__ X,    // bf16 [M,128]
        const unsigned short* __restrict__ WcT,  // bf16 [o][k]
        const unsigned short* __restrict__ WfT,  // bf16 [p][o]
        const float* __restrict__ b_coarse,
        const float* __restrict__ b_fineout,
        const float* __restrict__ gate,          // [B*h*w]
        float* __restrict__ out) {
    __shared__ unsigned short Xs[64 * LDSP];
    __shared__ unsigned short Ws[128 * LDSP];
    int tid = threadIdx.x;
    int row0 = blockIdx.x * 64;

    {
        const uint4* src = (const uint4*)(X + (size_t)row0 * 128);
        for (int ci = tid; ci < 1024; ci += 256) {
            int r = ci >> 4, c = ci & 15;
            *(uint4*)(&Xs[r * LDSP + c * 8]) = src[ci];
        }
        const uint4* wsrc = (const uint4*)WcT;
        for (int ci = tid; ci < 2048; ci += 256) {
            int r = ci >> 4, c = ci & 15;
            *(uint4*)(&Ws[r * LDSP + c * 8]) = wsrc[ci];
        }
    }
    __syncthreads();

    int wid = tid >> 6, lane = tid & 63;
    int wm = wid >> 1, wn = wid & 1;
    int lr = lane & 15;
    int lk = (lane >> 4) * 8;
    int lrow4 = (lane >> 4) * 4;

    floatx4 acc1[2][4];
    #pragma unroll
    for (int mi = 0; mi < 2; ++mi)
        #pragma unroll
        for (int ni = 0; ni < 4; ++ni)
            acc1[mi][ni] = (floatx4){0.f, 0.f, 0.f, 0.f};

    #pragma unroll
    for (int kk = 0; kk < 128; kk += 32) {
        short8 a[2], bb[4];
        #pragma unroll
        for (int mi = 0; mi < 2; ++mi)
            a[mi] = *(const short8*)(&Xs[(wm * 32 + mi * 16 + lr) * LDSP + kk + lk]);
        #pragma unroll
        for (int ni = 0; ni < 4; ++ni)
            bb[ni] = *(const short8*)(&Ws[(wn * 64 + ni * 16 + lr) * LDSP + kk + lk]);
        #pragma unroll
        for (int mi = 0; mi < 2; ++mi)
            #pragma unroll
            for (int ni = 0; ni < 4; ++ni)
                acc1[mi][ni] = __builtin_amdgcn_mfma_f32_16x16x32_bf16(a[mi], bb[ni], acc1[mi][ni], 0, 0, 0);
    }
    __syncthreads();

    {
        const uint4* wsrc = (const uint4*)WfT;
        for (int ci = tid; ci < 2048; ci += 256) {
            int r = ci >> 4, c = ci & 15;
            *(uint4*)(&Ws[r * LDSP + c * 8]) = wsrc[ci];
        }
    }
    #pragma unroll
    for (int mi = 0; mi < 2; ++mi) {
        #pragma unroll
        for (int ni = 0; ni < 4; ++ni) {
            int col = wn * 64 + ni * 16 + lr;
            float bc = b_coarse[col];
            #pragma unroll
            for (int j = 0; j < 4; ++j) {
                int row = wm * 32 + mi * 16 + lrow4 + j;
                float v = acc1[mi][ni][j] + bc;
                acc1[mi][ni][j] = v;
                Xs[row * LDSP + col] = f32_to_bf16(v);
            }
        }
    }
    __syncthreads();

    floatx4 acc2[2][4];
    #pragma unroll
    for (int mi = 0; mi < 2; ++mi)
        #pragma unroll
        for (int ni = 0; ni < 4; ++ni)
            acc2[mi][ni] = (floatx4){0.f, 0.f, 0.f, 0.f};

    #pragma unroll
    for (int kk = 0; kk < 128; kk += 32) {
        short8 a[2], bb[4];
        #pragma unroll
        for (int mi = 0; mi < 2; ++mi)
            a[mi] = *(const short8*)(&Xs[(wm * 32 + mi * 16 + lr) * LDSP + kk + lk]);
        #pragma unroll
        for (int ni = 0; ni < 4; ++ni)
            bb[ni] = *(const short8*)(&Ws[(wn * 64 + ni * 16 + lr) * LDSP + kk + lk]);
        #pragma unroll
        for (int mi = 0; mi < 2; ++mi)
            #pragma unroll
            for (int ni = 0; ni < 4; ++ni)
                acc2[mi][ni] = __builtin_amdgcn_mfma_f32_16x16x32_bf16(a[mi], bb[ni], acc2[mi][ni], 0, 0, 0);
    }

    #pragma unroll
    for (int mi = 0; mi < 2; ++mi) {
        #pragma unroll
        for (int ni = 0; ni < 4; ++ni) {
            int col = wn * 64 + ni * 16 + lr;
            float bf = b_fineout[col];
            #pragma unroll
            for (int j = 0; j < 4; ++j) {
                int row = wm * 32 + mi * 16 + lrow4 + j;
                int q = row0 + row;
                int b = q >> 14;
                int remq = q & 16383;
                int fy = remq >> 7, fx = remq & 127;
                float g = gate[(b << 12) + ((fy >> 1) << 6) + (fx >> 1)];
                float co = acc1[mi][ni][j];
                float fo = acc2[mi][ni][j] + bf;
                out[(size_t)q * FILTERS + col] = g * fo + (1.0f - g) * co;
            }
        }
    }
}

extern "C" void kernel_launch(void* const* d_in, const int* in_sizes, int n_in,
                              void* d_out, int out_size, void* d_ws, size_t ws_size,
                              hipStream_t stream) {
    const float* fine      = (const float*)d_in[0];
    const float* coarse    = (const float*)d_in[1];
    const float* w_gate    = (const float*)d_in[2];
    const float* b_gate    = (const float*)d_in[3];
    const float* w_sfine   = (const float*)d_in[4];
    const float* w_scoarse = (const float*)d_in[5];
    const float* b_scoarse = (const float*)d_in[6];
    const float* w_content = (const float*)d_in[7];
    const float* b_content = (const float*)d_in[8];
    const float* w_coarse  = (const float*)d_in[9];
    const float* b_coarse  = (const float*)d_in[10];
    const float* w_fineout = (const float*)d_in[11];
    const float* b_fineout = (const float*)d_in[12];
    float* out = (float*)d_out;

    const int B = 2, H = 128, W = 128, h = 64, w = 64;
    const int MF = B * H * W;   // 32768
    const int MC = B * h * w;   // 8192

    char* ws = (char*)d_ws;
    size_t off = 0;
    auto alloc = [&](size_t bytes) {
        void* p = ws + off;
        off = (off + bytes + 255) & ~(size_t)255;
        return p;
    };
    float* g_gate            = (float*)alloc((size_t)MC * 4);
    unsigned short* f_emb    = (unsigned short*)alloc((size_t)MF * EMB * 2);
    unsigned short* c_emb    = (unsigned short*)alloc((size_t)MC * EMB * 2);
    float* f_conv            = (float*)alloc((size_t)MF * KK * 4);
    float* c_conv            = (float*)alloc((size_t)MC * KK * 4);
    unsigned short* x_bf16   = (unsigned short*)alloc((size_t)MF * CC * 2);
    unsigned short* wsfT     = (unsigned short*)alloc(64 * 128 * 2);
    unsigned short* wscT     = (unsigned short*)alloc(64 * 128 * 2);
    unsigned short* wconT    = (unsigned short*)alloc(32 * 576 * 2);
    unsigned short* wcT      = (unsigned short*)alloc(128 * 128 * 2);
    unsigned short* wfT      = (unsigned short*)alloc(128 * 128 * 2);

    const int NEF = MF / 128;         // 256 fine embed blocks
    const int NEC = MC / 128;         // 64 coarse embed blocks
    const int NCF = B * (H / 4) * (W / 32);   // 256 fine content blocks
    const int NCC = B * (h / 4) * (w / 32);   // 64 coarse content blocks

    wtrans_all_kernel<<<264, 256, 0, stream>>>(w_sfine, w_scoarse, w_content, w_coarse, w_fineout,
                                               wsfT, wscT, wconT, wcT, wfT);
    embed_both_kernel<<<NEF + NEC, 256, 0, stream>>>(fine, wsfT, coarse, wscT, b_scoarse,
                                                     f_emb, c_emb, NEF);
    content_both_kernel<<<NCF + NCC, 256, 0, stream>>>(f_emb, c_emb, wconT, b_content,
                                                       f_conv, c_conv, NCF);
    carafe_gate_kernel<<<MC, 256, 0, stream>>>(coarse, f_conv, c_conv, w_gate, b_gate,
                                               x_bf16, g_gate, h, w);
    final_kernel<<<MF / 64, 256, 0, stream>>>(x_bf16, wcT, wfT, b_coarse, b_fineout, g_gate, out);
}